// Round 1
// baseline (187.908 us; speedup 1.0000x reference)
//
#include <hip/hip_runtime.h>

#define R 4096
#define NN 48
#define NP 49        // N+1
#define C 98         // 2N+2
#define NSEG 65536
#define MM (R * NN)  // 196608

// ---------------------------------------------------------------------------
// Per-row kernel: rgb loss + both inter-level losses + distortion loss.
// One block of 128 threads per row.
// ---------------------------------------------------------------------------
__global__ __launch_bounds__(128) void row_kernel(
    const float* __restrict__ pd, const float* __restrict__ gt,
    const float* __restrict__ sdist_g, const float* __restrict__ w_g,
    const float* __restrict__ ps0, const float* __restrict__ pwt0,
    const float* __restrict__ ps1, const float* __restrict__ pwt1,
    float* __restrict__ acc)
{
    __shared__ float s_sd[NP], s_wn[NN], s_w[NN], s_mid[NN];
    __shared__ float s_bounds[C], s_rs[C], s_wb[C], s_cdf[C];
    __shared__ int   s_fe[C];
    __shared__ float s_ci[257];
    __shared__ float s_red[128];

    const int r = blockIdx.x;
    const int tid = threadIdx.x;
    float local = 0.f;

    if (tid < NP) s_sd[tid] = sdist_g[r * NP + tid];
    if (tid < NN) s_w[tid] = w_g[r * NN + tid];
    __syncthreads();
    if (tid < NN) {
        s_wn[tid]  = s_w[tid] / (s_sd[tid + 1] - s_sd[tid] + 1e-8f);
        s_mid[tid] = 0.5f * (s_sd[tid + 1] + s_sd[tid]);
    }
    __syncthreads();

    for (int lvl = 0; lvl < 2; ++lvl) {
        const float pw = (lvl == 0) ? 0.01f : 0.005f;
        const int X = (lvl == 0) ? 257 : 97;
        const float* ps  = (lvl == 0) ? ps0 : ps1;
        const float* pwt = (lvl == 0) ? pwt0 : pwt1;

        // ---- stable merge-rank of cat = [sdist-pw, sdist+pw], scatter ----
        if (tid < C) {
            float val, rd;
            int rank;
            if (tid < NP) {
                const int i = tid;
                val = s_sd[i] - pw;
                const float dlo = (i > 0)  ? s_wn[i - 1] : 0.f;
                const float dhi = (i < NN) ? s_wn[i] : 0.f;
                rd = (dhi - dlo) / (2.f * pw);
                // count second-half values (sd+pw) strictly < val
                int lo = 0, hi = NP;
                while (lo < hi) { int m = (lo + hi) >> 1; if (s_sd[m] + pw < val) lo = m + 1; else hi = m; }
                rank = i + lo;
            } else {
                const int k = tid - NP;
                val = s_sd[k] + pw;
                const float dlo = (k > 0)  ? s_wn[k - 1] : 0.f;
                const float dhi = (k < NN) ? s_wn[k] : 0.f;
                rd = -((dhi - dlo) / (2.f * pw));
                // count first-half values (sd-pw) <= val  (first half wins ties)
                int lo = 0, hi = NP;
                while (lo < hi) { int m = (lo + hi) >> 1; if (s_sd[m] - pw <= val) lo = m + 1; else hi = m; }
                rank = k + lo;
            }
            s_bounds[rank] = val;
            s_rs[rank] = rd;
        }
        __syncthreads();

        // ---- serial scans (match reference float32 sequential order) ----
        if (tid == 0) {
            float cum1 = 0.f, acc2 = 0.f, cdfa = 0.f, wprev = 0.f, cdfprev = 0.f;
            int feprev = 0;
            s_wb[0] = 0.f; s_cdf[0] = 0.f; s_fe[0] = 0;
            for (int k = 0; k < C - 1; ++k) {
                cum1 += s_rs[k];
                const float ds = s_bounds[k + 1] - s_bounds[k];
                acc2 += ds * cum1;
                const float rec = fmaxf(acc2, 0.f);
                cdfa += 0.5f * (rec + wprev) * ds;
                s_wb[k + 1] = rec;
                s_cdf[k + 1] = cdfa;
                const int fe = (cdfa == cdfprev) ? feprev : (k + 1);
                s_fe[k + 1] = fe;
                wprev = rec; cdfprev = cdfa; feprev = fe;
            }
        }
        __syncthreads();

        // ---- sorted_interp_quad, exact argmax/argmin tie semantics ----
        for (int t = tid; t < X; t += 128) {
            const float x = ps[r * X + t];
            int lo = 0, hi = C;
            while (lo < hi) { int m = (lo + hi) >> 1; if (s_bounds[m] <= x) lo = m + 1; else hi = m; }
            const int j = lo - 1;  // largest p with bounds[p] <= x, or -1
            float res;
            if (j < 0) {
                // fcdf0=cdf[0]=0, fpdf0=fpdf1=w_b[0]=0, offset->0 => result 0
                res = 0.f;
            } else {
                const float fcdf0 = s_cdf[j];
                const int   i0   = s_fe[j];       // argmax tie -> plateau start
                const float xp0  = s_bounds[j];
                float xp1; int i1;
                if (j == C - 1) { xp1 = s_bounds[C - 1]; i1 = 0; }
                else {
                    xp1 = s_bounds[j + 1];
                    i1 = (s_cdf[j + 1] == s_cdf[C - 1]) ? 0 : (j + 1);  // flat-tail tie
                }
                const float fpdf0 = s_wb[i0], fpdf1 = s_wb[i1];
                const float dx = x - xp0, den = xp1 - xp0;
                float off;
                if (den != 0.f) off = dx / den;
                else off = (dx == 0.f) ? 0.f : ((dx > 0.f) ? 1.f : 0.f);  // nan_to_num + clip
                off = fminf(fmaxf(off, 0.f), 1.f);
                res = fcdf0 + dx * (fpdf0 + fpdf1 * off + fpdf0 * (1.f - off)) * 0.5f;
            }
            s_ci[t] = res;
        }
        __syncthreads();

        float lsum = 0.f;
        for (int t = tid; t < X - 1; t += 128) {
            const float ws = s_ci[t + 1] - s_ci[t];
            const float pv = pwt[r * (X - 1) + t];
            const float d = fmaxf(ws - pv, 0.f);
            lsum += d * d / (pv + 1e-5f);
        }
        local += lsum * (1.0f / ((float)R * (float)(X - 1)));  // W_INTER = 1
        __syncthreads();  // before LDS reuse by next level
    }

    // ---- distortion loss (all terms non-negative -> abs is identity) ----
    float p1 = 0.f;
    for (int t = tid; t < NN * NN; t += 128) {
        const int n = t / NN, m2 = t - n * NN;
        p1 += s_w[n] * s_w[m2] * fabsf(s_mid[n] - s_mid[m2]);
    }
    local += p1 * (0.01f / (float)R);
    if (tid < NN) {
        const float dd = s_sd[tid + 1] - s_sd[tid];
        local += (s_w[tid] * s_w[tid] * dd) * (0.01f / (3.f * (float)R));
    }

    // ---- rgb loss ----
    if (tid < 3) {
        const float e = pd[r * 3 + tid] - gt[r * 3 + tid];
        local += e * e * (1.0f / ((float)R * 3.f));
    }

    // ---- block reduce + single atomic ----
    s_red[tid] = local;
    __syncthreads();
    for (int s = 64; s > 0; s >>= 1) {
        if (tid < s) s_red[tid] += s_red[tid + s];
        __syncthreads();
    }
    if (tid == 0) atomicAdd(acc, s_red[0]);
}

// ---------------------------------------------------------------------------
// Hash decay: idx is sorted -> segments are contiguous runs; thread at each
// run start walks the run. No segment arrays needed.
// ---------------------------------------------------------------------------
__global__ __launch_bounds__(256) void hash_kernel(const float* __restrict__ emb,
                                                   const int* __restrict__ idx,
                                                   float* __restrict__ acc)
{
    const int i = blockIdx.x * 256 + threadIdx.x;
    float local = 0.f;
    if (i < MM) {
        const int seg = idx[i];
        if (i == 0 || idx[i - 1] != seg) {
            float s = 0.f;
            int j = i;
            while (j < MM && idx[j] == seg) {
                const float a = emb[2 * j], b = emb[2 * j + 1];
                s += a * a + b * b;
                ++j;
            }
            local = s / (float)(j - i);
        }
    }
    __shared__ float sred[256];
    sred[threadIdx.x] = local;
    __syncthreads();
    for (int s = 128; s > 0; s >>= 1) {
        if (threadIdx.x < s) sred[threadIdx.x] += sred[threadIdx.x + s];
        __syncthreads();
    }
    if (threadIdx.x == 0)
        atomicAdd(acc, sred[0] * (0.1f / ((float)NSEG * 2.f)));  // W_HASH / (NSEG*2)
}

__global__ void finalize_kernel(const float* __restrict__ acc, float* __restrict__ out)
{
    out[0] = acc[0];
}

extern "C" void kernel_launch(void* const* d_in, const int* in_sizes, int n_in,
                              void* d_out, int out_size, void* d_ws, size_t ws_size,
                              hipStream_t stream)
{
    const float* pd  = (const float*)d_in[0];
    const float* gt  = (const float*)d_in[1];
    const float* sd  = (const float*)d_in[2];
    const float* w   = (const float*)d_in[3];
    const float* ps0 = (const float*)d_in[4];
    const float* pw0 = (const float*)d_in[5];
    const float* ps1 = (const float*)d_in[6];
    const float* pw1 = (const float*)d_in[7];
    const float* e0  = (const float*)d_in[8];
    const float* e1  = (const float*)d_in[9];
    const int* i0    = (const int*)d_in[10];
    const int* i1    = (const int*)d_in[11];

    float* acc = (float*)d_ws;
    (void)hipMemsetAsync(d_ws, 0, 64, stream);

    hipLaunchKernelGGL(row_kernel, dim3(R), dim3(128), 0, stream,
                       pd, gt, sd, w, ps0, pw0, ps1, pw1, acc);
    hipLaunchKernelGGL(hash_kernel, dim3((MM + 255) / 256), dim3(256), 0, stream, e0, i0, acc);
    hipLaunchKernelGGL(hash_kernel, dim3((MM + 255) / 256), dim3(256), 0, stream, e1, i1, acc);
    hipLaunchKernelGGL(finalize_kernel, dim3(1), dim3(1), 0, stream, acc, (float*)d_out);
}

// Round 2
// 158.279 us; speedup vs baseline: 1.1872x; 1.1872x over previous
//
#include <hip/hip_runtime.h>

#define R 4096
#define NN 48
#define NP 49        // N+1
#define C 98         // 2N+2
#define NSEG 65536
#define MM (R * NN)  // 196608
#define RPB 4        // rows (waves) per block

__device__ __forceinline__ float wscan_add(float v, int lane) {
#pragma unroll
    for (int d = 1; d < 64; d <<= 1) {
        float t = __shfl_up(v, d, 64);
        if (lane >= d) v += t;
    }
    return v;
}

__device__ __forceinline__ int wscan_max(int v, int lane) {
#pragma unroll
    for (int d = 1; d < 64; d <<= 1) {
        int t = __shfl_up(v, d, 64);
        if (lane >= d) v = max(v, t);
    }
    return v;
}

// ---------------------------------------------------------------------------
// One wave (64 lanes) per row; 4 rows per 256-thread block.
// All cumsum/max-scan chains are wave shuffle scans (2 elements per lane).
// ---------------------------------------------------------------------------
__global__ __launch_bounds__(256) void row_kernel(
    const float* __restrict__ pd, const float* __restrict__ gt,
    const float* __restrict__ sdist_g, const float* __restrict__ w_g,
    const float* __restrict__ ps0, const float* __restrict__ pwt0,
    const float* __restrict__ ps1, const float* __restrict__ pwt1,
    float* __restrict__ acc)
{
    __shared__ float s_sd[RPB][NP];
    __shared__ float s_wn[RPB][NN];
    __shared__ float s_w[RPB][NN];
    __shared__ float s_mid[RPB][NN];
    __shared__ float s_bounds[RPB][C];
    __shared__ float s_rs[RPB][C];
    __shared__ float s_wb[RPB][C];
    __shared__ float s_cdf[RPB][C];
    __shared__ int   s_fe[RPB][C];
    __shared__ float s_ci[RPB][260];
    __shared__ float s_red[RPB];

    const int wid = threadIdx.x >> 6;
    const int lane = threadIdx.x & 63;
    const int r = blockIdx.x * RPB + wid;

    float* sd  = s_sd[wid];
    float* wn  = s_wn[wid];
    float* w   = s_w[wid];
    float* mid = s_mid[wid];
    float* bounds = s_bounds[wid];
    float* rs  = s_rs[wid];
    float* wb  = s_wb[wid];
    float* cdf = s_cdf[wid];
    int*   fe  = s_fe[wid];
    float* ci  = s_ci[wid];

    if (lane < NP) sd[lane] = sdist_g[r * NP + lane];
    if (lane < NN) w[lane] = w_g[r * NN + lane];
    __syncthreads();
    if (lane < NN) {
        wn[lane]  = w[lane] / (sd[lane + 1] - sd[lane] + 1e-8f);
        mid[lane] = 0.5f * (sd[lane + 1] + sd[lane]);
    }
    __syncthreads();

    float local = 0.f;

#pragma unroll
    for (int lvl = 0; lvl < 2; ++lvl) {
        const float pw = (lvl == 0) ? 0.01f : 0.005f;
        const int X = (lvl == 0) ? 257 : 97;
        const float* ps  = (lvl == 0) ? ps0 : ps1;
        const float* pwt = (lvl == 0) ? pwt0 : pwt1;

        // ---- stable merge-rank of cat = [sd-pw, sd+pw]; scatter ----
        if (lane < NP) {
            const int i = lane;
            const float dlo = (i > 0)  ? wn[i - 1] : 0.f;
            const float dhi = (i < NN) ? wn[i] : 0.f;
            const float rd = (dhi - dlo) / (2.f * pw);
            const float vlo = sd[i] - pw, vhi = sd[i] + pw;
            int lo = 0, hi = NP;  // count second-half strictly < vlo
            while (lo < hi) { int m = (lo + hi) >> 1; if (sd[m] + pw < vlo) lo = m + 1; else hi = m; }
            const int rlo = i + lo;
            lo = 0; hi = NP;      // count first-half <= vhi (first half wins ties)
            while (lo < hi) { int m = (lo + hi) >> 1; if (sd[m] - pw <= vhi) lo = m + 1; else hi = m; }
            const int rhi = i + lo;
            bounds[rlo] = vlo; rs[rlo] = rd;
            bounds[rhi] = vhi; rs[rhi] = -rd;
        }
        __syncthreads();

        // ---- parallel scans: lane holds scan elements k0=2*lane, k1=2*lane+1 (k<=96) ----
        const int k0 = 2 * lane, k1 = 2 * lane + 1;
        const bool v0 = (k0 <= C - 2), v1 = (k1 <= C - 2);
        float b0 = 0.f, b1 = 0.f, b2 = 0.f, r0 = 0.f, r1 = 0.f;
        if (v0) { b0 = bounds[k0]; b1 = bounds[k0 + 1]; r0 = rs[k0]; }
        if (v1) { b2 = bounds[k1 + 1]; r1 = rs[k1]; }
        const float ds0 = b1 - b0, ds1 = b2 - b1;

        // scan 1: cum1 = cumsum(radio_sorted)
        float pairv = r0 + r1;
        float incl = wscan_add(pairv, lane);
        float excl = __shfl_up(incl, 1, 64); if (lane == 0) excl = 0.f;
        const float cum0 = excl + r0, cum1 = excl + pairv;

        // scan 2: acc2 = cumsum(ds * cum1); rec = max(acc2, 0)
        float y0 = v0 ? ds0 * cum0 : 0.f;
        float y1 = v1 ? ds1 * cum1 : 0.f;
        pairv = y0 + y1;
        incl = wscan_add(pairv, lane);
        excl = __shfl_up(incl, 1, 64); if (lane == 0) excl = 0.f;
        const float rec0 = v0 ? fmaxf(excl + y0, 0.f) : 0.f;
        const float rec1 = v1 ? fmaxf(excl + pairv, 0.f) : 0.f;

        // scan 3: cdf = cumsum(0.5*(rec[k]+rec[k-1])*ds[k]),  rec[-1] = wb[0] = 0
        float rprev = __shfl_up(rec1, 1, 64); if (lane == 0) rprev = 0.f;
        float t0 = v0 ? 0.5f * (rec0 + rprev) * ds0 : 0.f;
        float t1 = v1 ? 0.5f * (rec1 + rec0) * ds1 : 0.f;
        pairv = t0 + t1;
        incl = wscan_add(pairv, lane);
        excl = __shfl_up(incl, 1, 64); if (lane == 0) excl = 0.f;
        const float c0 = excl + t0;     // cdf[j0], j0 = k0+1
        const float c1 = excl + pairv;  // cdf[j1], j1 = k1+1

        // first_eq (plateau start) = inclusive max-scan of (changed ? j : 0)
        float cprev = __shfl_up(c1, 1, 64); if (lane == 0) cprev = 0.f;
        const int j0 = k0 + 1, j1 = k1 + 1;
        const int m0 = (v0 && c0 != cprev) ? j0 : 0;
        const int m1 = (v1 && c1 != c0) ? j1 : 0;
        int pm = max(m0, m1);
        int inclm = wscan_max(pm, lane);
        int exclm = __shfl_up(inclm, 1, 64); if (lane == 0) exclm = 0;

        if (lane == 0) { wb[0] = 0.f; cdf[0] = 0.f; fe[0] = 0; }
        if (v0) { wb[j0] = rec0; cdf[j0] = c0; fe[j0] = max(exclm, m0); }
        if (v1) { wb[j1] = rec1; cdf[j1] = c1; fe[j1] = max(exclm, pm); }
        __syncthreads();

        // ---- sorted_interp_quad, exact argmax/argmin tie semantics ----
        for (int t = lane; t < X; t += 64) {
            const float x = ps[r * X + t];
            int lo = 0, hi = C;
            while (lo < hi) { int m = (lo + hi) >> 1; if (bounds[m] <= x) lo = m + 1; else hi = m; }
            const int j = lo - 1;  // largest p with bounds[p] <= x, or -1
            float res = 0.f;
            if (j >= 0) {
                const float fcdf0 = cdf[j];
                const int   i0   = fe[j];          // argmax tie -> plateau start
                const float xp0  = bounds[j];
                float xp1; int i1;
                if (j == C - 1) { xp1 = bounds[C - 1]; i1 = 0; }
                else {
                    xp1 = bounds[j + 1];
                    i1 = (cdf[j + 1] == cdf[C - 1]) ? 0 : (j + 1);  // flat-tail tie
                }
                const float fpdf0 = wb[i0], fpdf1 = wb[i1];
                const float dx = x - xp0, den = xp1 - xp0;
                float off;
                if (den != 0.f) off = dx / den;
                else off = (dx == 0.f) ? 0.f : ((dx > 0.f) ? 1.f : 0.f);  // nan_to_num + clip
                off = fminf(fmaxf(off, 0.f), 1.f);
                res = fcdf0 + dx * (fpdf0 + fpdf1 * off + fpdf0 * (1.f - off)) * 0.5f;
            }
            ci[t] = res;
        }
        __syncthreads();

        float lsum = 0.f;
        for (int t = lane; t < X - 1; t += 64) {
            const float ws = ci[t + 1] - ci[t];
            const float pv = pwt[r * (X - 1) + t];
            const float d = fmaxf(ws - pv, 0.f);
            lsum += d * d / (pv + 1e-5f);
        }
        local += lsum * (1.0f / ((float)R * (float)(X - 1)));  // W_INTER = 1
        __syncthreads();  // before LDS reuse by next level
    }

    // ---- distortion loss (all terms non-negative -> abs is identity) ----
    float p1 = 0.f;
    for (int t = lane; t < NN * NN; t += 64) {
        const int n = t / NN, m2 = t - n * NN;
        p1 += w[n] * w[m2] * fabsf(mid[n] - mid[m2]);
    }
    local += p1 * (0.01f / (float)R);
    if (lane < NN) {
        const float dd = sd[lane + 1] - sd[lane];
        local += (w[lane] * w[lane] * dd) * (0.01f / (3.f * (float)R));
    }

    // ---- rgb loss ----
    if (lane < 3) {
        const float e = pd[r * 3 + lane] - gt[r * 3 + lane];
        local += e * e * (1.0f / ((float)R * 3.f));
    }

    // ---- wave reduce, then one atomic per block ----
#pragma unroll
    for (int d = 32; d > 0; d >>= 1) local += __shfl_down(local, d, 64);
    if (lane == 0) s_red[wid] = local;
    __syncthreads();
    if (threadIdx.x == 0)
        atomicAdd(acc, s_red[0] + s_red[1] + s_red[2] + s_red[3]);
}

// ---------------------------------------------------------------------------
// Both hash levels in one kernel; last block to finish writes the final sum.
// idx is sorted -> segments are contiguous runs; thread at run start walks it.
// ---------------------------------------------------------------------------
#define HB ((MM + 255) / 256)  // blocks per level = 768

__global__ __launch_bounds__(256) void hash_fin_kernel(
    const float* __restrict__ e0, const int* __restrict__ idx0,
    const float* __restrict__ e1, const int* __restrict__ idx1,
    float* __restrict__ acc, unsigned int* __restrict__ counter,
    float* __restrict__ out)
{
    const int b = blockIdx.x;
    const float* emb = (b < HB) ? e0 : e1;
    const int*   idx = (b < HB) ? idx0 : idx1;
    const int base = ((b < HB) ? b : (b - HB)) * 256;
    const int i = base + threadIdx.x;

    float local = 0.f;
    if (i < MM) {
        const int seg = idx[i];
        if (i == 0 || idx[i - 1] != seg) {
            float s = 0.f;
            int j = i;
            while (j < MM && idx[j] == seg) {
                const float a = emb[2 * j], c = emb[2 * j + 1];
                s += a * a + c * c;
                ++j;
            }
            local = s / (float)(j - i);
        }
    }

    const int lane = threadIdx.x & 63;
#pragma unroll
    for (int d = 32; d > 0; d >>= 1) local += __shfl_down(local, d, 64);
    __shared__ float sred[4];
    if (lane == 0) sred[threadIdx.x >> 6] = local;
    __syncthreads();
    if (threadIdx.x == 0) {
        const float v = (sred[0] + sred[1] + sred[2] + sred[3]) * (0.1f / ((float)NSEG * 2.f));
        atomicAdd(acc, v);
        __threadfence();
        const unsigned int old = atomicAdd(counter, 1u);
        if (old == gridDim.x - 1) {
            out[0] = atomicAdd(acc, 0.f);  // returns final sum (all adds precede)
        }
    }
}

extern "C" void kernel_launch(void* const* d_in, const int* in_sizes, int n_in,
                              void* d_out, int out_size, void* d_ws, size_t ws_size,
                              hipStream_t stream)
{
    const float* pd  = (const float*)d_in[0];
    const float* gt  = (const float*)d_in[1];
    const float* sd  = (const float*)d_in[2];
    const float* w   = (const float*)d_in[3];
    const float* ps0 = (const float*)d_in[4];
    const float* pw0 = (const float*)d_in[5];
    const float* ps1 = (const float*)d_in[6];
    const float* pw1 = (const float*)d_in[7];
    const float* e0  = (const float*)d_in[8];
    const float* e1  = (const float*)d_in[9];
    const int* i0    = (const int*)d_in[10];
    const int* i1    = (const int*)d_in[11];

    float* acc = (float*)d_ws;
    unsigned int* counter = (unsigned int*)((char*)d_ws + 16);
    (void)hipMemsetAsync(d_ws, 0, 64, stream);

    hipLaunchKernelGGL(row_kernel, dim3(R / RPB), dim3(256), 0, stream,
                       pd, gt, sd, w, ps0, pw0, ps1, pw1, acc);
    hipLaunchKernelGGL(hash_fin_kernel, dim3(2 * HB), dim3(256), 0, stream,
                       e0, i0, e1, i1, acc, counter, (float*)d_out);
}

// Round 3
// 108.821 us; speedup vs baseline: 1.7268x; 1.4545x over previous
//
#include <hip/hip_runtime.h>

#define R 4096
#define NN 48
#define NP 49        // N+1
#define C 98         // 2N+2
#define NSEG 65536
#define MM (R * NN)  // 196608
#define RPB 4        // rows (waves) per row-block
#define GB_ROW (R / RPB)            // 1024
#define GB_HASH (MM / 256)          // 768 per level
#define GRID (GB_ROW + 2 * GB_HASH) // 2560

__device__ __forceinline__ float wscan_add(float v, int lane) {
#pragma unroll
    for (int d = 1; d < 64; d <<= 1) {
        float t = __shfl_up(v, d, 64);
        if (lane >= d) v += t;
    }
    return v;
}

__device__ __forceinline__ int wscan_max(int v, int lane) {
#pragma unroll
    for (int d = 1; d < 64; d <<= 1) {
        int t = __shfl_up(v, d, 64);
        if (lane >= d) v = max(v, t);
    }
    return v;
}

// ---------------------------------------------------------------------------
// Fused kernel. Blocks [0, GB_ROW): per-row losses (1 wave per row, 4 rows).
// Blocks [GB_ROW, GRID): hash-decay, 256 elements each, ballot-based run
// lengths (no serial walks, no atomics). Every block writes partial[b].
// ---------------------------------------------------------------------------
__global__ __launch_bounds__(256) void fused_kernel(
    const float* __restrict__ pd, const float* __restrict__ gt,
    const float* __restrict__ sdist_g, const float* __restrict__ w_g,
    const float* __restrict__ ps0, const float* __restrict__ pwt0,
    const float* __restrict__ ps1, const float* __restrict__ pwt1,
    const float* __restrict__ e0, const int* __restrict__ idx0,
    const float* __restrict__ e1, const int* __restrict__ idx1,
    float* __restrict__ partial)
{
    __shared__ float s_sd[RPB][NP];
    __shared__ float s_wn[RPB][NN];
    __shared__ float s_w[RPB][NN];
    __shared__ float s_mid[RPB][NN];
    __shared__ float s_bounds[RPB][C];
    __shared__ float s_rs[RPB][C];
    __shared__ float s_wb[RPB][C];
    __shared__ float s_cdf[RPB][C];
    __shared__ int   s_fe[RPB][C];
    __shared__ float s_ci[RPB][260];
    __shared__ float s_red[RPB];
    __shared__ unsigned long long s_masks[6];

    const int tid = threadIdx.x;
    const int wid = tid >> 6;
    const int lane = tid & 63;

    if (blockIdx.x >= GB_ROW) {
        // ================= HASH part =================
        const int h = blockIdx.x - GB_ROW;
        const int lvlh = (h >= GB_HASH);
        const float* __restrict__ emb = lvlh ? e1 : e0;
        const int*   __restrict__ idx = lvlh ? idx1 : idx0;
        const int base = (lvlh ? h - GB_HASH : h) * 256;
        const int i = base + tid;

        const int seg = idx[i];
        const int head = (i == 0) || (idx[i - 1] != seg);
        unsigned long long m = __ballot(head);
        if (lane == 0) s_masks[wid + 1] = m;
        if (wid == 0) {
            const int j = base - 64 + lane;
            int hh = 0;
            if (j == 0) hh = 1;
            else if (j > 0) hh = (idx[j - 1] != idx[j]);
            unsigned long long mp = __ballot(hh);
            if (lane == 0) s_masks[0] = mp;
        }
        if (wid == 3) {
            const int j = base + 256 + lane;
            int hh = 1;                       // j >= MM: virtual terminator head
            if (j < MM) hh = (idx[j - 1] != idx[j]);
            unsigned long long mn = __ballot(hh);
            if (lane == 0) s_masks[5] = mn;
        }
        __syncthreads();

        const unsigned long long m_prev = s_masks[wid];
        const unsigned long long m_cur  = s_masks[wid + 1];
        const unsigned long long m_next = s_masks[wid + 2];
        const int wb0 = base + (wid << 6);

        const unsigned long long low = m_cur & (~0ULL >> (63 - lane));
        int s;
        if (low) s = wb0 + 63 - __builtin_clzll(low);
        else if (m_prev) s = wb0 - 64 + 63 - __builtin_clzll(m_prev);
        else { s = i; while (s > 0 && idx[s - 1] == seg) --s; }  // run > 128: never

        const unsigned long long high =
            (lane < 63) ? (m_cur & (~0ULL << (lane + 1))) : 0ULL;
        int e;
        if (high) e = wb0 + __builtin_ctzll(high);
        else if (m_next) e = wb0 + 64 + __builtin_ctzll(m_next);
        else { e = i + 1; while (e < MM && idx[e] == seg) ++e; }  // never

        const float a = emb[2 * i], b = emb[2 * i + 1];
        float v = (a * a + b * b) / (float)(e - s);

#pragma unroll
        for (int d = 32; d > 0; d >>= 1) v += __shfl_down(v, d, 64);
        if (lane == 0) s_red[wid] = v;
        __syncthreads();
        if (tid == 0)
            partial[blockIdx.x] =
                (s_red[0] + s_red[1] + s_red[2] + s_red[3]) *
                (0.1f / ((float)NSEG * 2.f));
        return;
    }

    // ================= ROW part =================
    const int r = blockIdx.x * RPB + wid;

    float* sd  = s_sd[wid];
    float* wn  = s_wn[wid];
    float* w   = s_w[wid];
    float* mid = s_mid[wid];
    float* bounds = s_bounds[wid];
    float* rs  = s_rs[wid];
    float* wb  = s_wb[wid];
    float* cdf = s_cdf[wid];
    int*   fe  = s_fe[wid];
    float* ci  = s_ci[wid];

    if (lane < NP) sd[lane] = sdist_g[r * NP + lane];
    if (lane < NN) w[lane] = w_g[r * NN + lane];
    __syncthreads();
    if (lane < NN) {
        wn[lane]  = w[lane] / (sd[lane + 1] - sd[lane] + 1e-8f);
        mid[lane] = 0.5f * (sd[lane + 1] + sd[lane]);
    }
    __syncthreads();

    float local = 0.f;

#pragma unroll
    for (int lvl = 0; lvl < 2; ++lvl) {
        const float pw = (lvl == 0) ? 0.01f : 0.005f;
        const int X = (lvl == 0) ? 257 : 97;
        const float* ps  = (lvl == 0) ? ps0 : ps1;
        const float* pwt = (lvl == 0) ? pwt0 : pwt1;

        // ---- stable merge-rank of cat = [sd-pw, sd+pw]; scatter ----
        if (lane < NP) {
            const int i = lane;
            const float dlo = (i > 0)  ? wn[i - 1] : 0.f;
            const float dhi = (i < NN) ? wn[i] : 0.f;
            const float rd = (dhi - dlo) / (2.f * pw);
            const float vlo = sd[i] - pw, vhi = sd[i] + pw;
            int lo = 0, hi = NP;  // count second-half strictly < vlo
            while (lo < hi) { int m = (lo + hi) >> 1; if (sd[m] + pw < vlo) lo = m + 1; else hi = m; }
            const int rlo = i + lo;
            lo = 0; hi = NP;      // count first-half <= vhi (first half wins ties)
            while (lo < hi) { int m = (lo + hi) >> 1; if (sd[m] - pw <= vhi) lo = m + 1; else hi = m; }
            const int rhi = i + lo;
            bounds[rlo] = vlo; rs[rlo] = rd;
            bounds[rhi] = vhi; rs[rhi] = -rd;
        }
        __syncthreads();

        // ---- parallel scans: lane holds elements k0=2*lane, k1=2*lane+1 ----
        const int k0 = 2 * lane, k1 = 2 * lane + 1;
        const bool v0 = (k0 <= C - 2), v1 = (k1 <= C - 2);
        float b0 = 0.f, b1 = 0.f, b2 = 0.f, r0 = 0.f, r1 = 0.f;
        if (v0) { b0 = bounds[k0]; b1 = bounds[k0 + 1]; r0 = rs[k0]; }
        if (v1) { b2 = bounds[k1 + 1]; r1 = rs[k1]; }
        const float ds0 = b1 - b0, ds1 = b2 - b1;

        // scan 1: cum1 = cumsum(radio_sorted)
        float pairv = r0 + r1;
        float incl = wscan_add(pairv, lane);
        float excl = __shfl_up(incl, 1, 64); if (lane == 0) excl = 0.f;
        const float cum0 = excl + r0, cum1 = excl + pairv;

        // scan 2: acc2 = cumsum(ds * cum1); rec = max(acc2, 0)
        float y0 = v0 ? ds0 * cum0 : 0.f;
        float y1 = v1 ? ds1 * cum1 : 0.f;
        pairv = y0 + y1;
        incl = wscan_add(pairv, lane);
        excl = __shfl_up(incl, 1, 64); if (lane == 0) excl = 0.f;
        const float rec0 = v0 ? fmaxf(excl + y0, 0.f) : 0.f;
        const float rec1 = v1 ? fmaxf(excl + pairv, 0.f) : 0.f;

        // scan 3: cdf = cumsum(0.5*(rec[k]+rec[k-1])*ds[k]), rec[-1]=0
        float rprev = __shfl_up(rec1, 1, 64); if (lane == 0) rprev = 0.f;
        float t0 = v0 ? 0.5f * (rec0 + rprev) * ds0 : 0.f;
        float t1 = v1 ? 0.5f * (rec1 + rec0) * ds1 : 0.f;
        pairv = t0 + t1;
        incl = wscan_add(pairv, lane);
        excl = __shfl_up(incl, 1, 64); if (lane == 0) excl = 0.f;
        const float c0 = excl + t0;     // cdf[j0], j0 = k0+1
        const float c1 = excl + pairv;  // cdf[j1], j1 = k1+1

        // first_eq (plateau start) = inclusive max-scan of (changed ? j : 0)
        float cprev = __shfl_up(c1, 1, 64); if (lane == 0) cprev = 0.f;
        const int j0 = k0 + 1, j1 = k1 + 1;
        const int m0 = (v0 && c0 != cprev) ? j0 : 0;
        const int m1 = (v1 && c1 != c0) ? j1 : 0;
        int pm = max(m0, m1);
        int inclm = wscan_max(pm, lane);
        int exclm = __shfl_up(inclm, 1, 64); if (lane == 0) exclm = 0;

        if (lane == 0) { wb[0] = 0.f; cdf[0] = 0.f; fe[0] = 0; }
        if (v0) { wb[j0] = rec0; cdf[j0] = c0; fe[j0] = max(exclm, m0); }
        if (v1) { wb[j1] = rec1; cdf[j1] = c1; fe[j1] = max(exclm, pm); }
        __syncthreads();

        // ---- sorted_interp_quad, exact argmax/argmin tie semantics ----
        for (int t = lane; t < X; t += 64) {
            const float x = ps[r * X + t];
            int lo = 0, hi = C;
            while (lo < hi) { int m = (lo + hi) >> 1; if (bounds[m] <= x) lo = m + 1; else hi = m; }
            const int j = lo - 1;  // largest p with bounds[p] <= x, or -1
            float res = 0.f;
            if (j >= 0) {
                const float fcdf0 = cdf[j];
                const int   i0   = fe[j];          // argmax tie -> plateau start
                const float xp0  = bounds[j];
                float xp1; int i1;
                if (j == C - 1) { xp1 = bounds[C - 1]; i1 = 0; }
                else {
                    xp1 = bounds[j + 1];
                    i1 = (cdf[j + 1] == cdf[C - 1]) ? 0 : (j + 1);  // flat-tail tie
                }
                const float fpdf0 = wb[i0], fpdf1 = wb[i1];
                const float dx = x - xp0, den = xp1 - xp0;
                float off;
                if (den != 0.f) off = dx / den;
                else off = (dx == 0.f) ? 0.f : ((dx > 0.f) ? 1.f : 0.f);
                off = fminf(fmaxf(off, 0.f), 1.f);
                res = fcdf0 + dx * (fpdf0 + fpdf1 * off + fpdf0 * (1.f - off)) * 0.5f;
            }
            ci[t] = res;
        }
        __syncthreads();

        float lsum = 0.f;
        for (int t = lane; t < X - 1; t += 64) {
            const float ws = ci[t + 1] - ci[t];
            const float pv = pwt[r * (X - 1) + t];
            const float d = fmaxf(ws - pv, 0.f);
            lsum += d * d / (pv + 1e-5f);
        }
        local += lsum * (1.0f / ((float)R * (float)(X - 1)));  // W_INTER = 1
        __syncthreads();  // before LDS reuse by next level
    }

    // ---- distortion loss (all terms non-negative -> abs is identity) ----
    float p1 = 0.f;
    for (int t = lane; t < NN * NN; t += 64) {
        const int n = t / NN, m2 = t - n * NN;
        p1 += w[n] * w[m2] * fabsf(mid[n] - mid[m2]);
    }
    local += p1 * (0.01f / (float)R);
    if (lane < NN) {
        const float dd = sd[lane + 1] - sd[lane];
        local += (w[lane] * w[lane] * dd) * (0.01f / (3.f * (float)R));
    }

    // ---- rgb loss ----
    if (lane < 3) {
        const float e = pd[r * 3 + lane] - gt[r * 3 + lane];
        local += e * e * (1.0f / ((float)R * 3.f));
    }

    // ---- wave reduce, write block partial (NO atomics) ----
#pragma unroll
    for (int d = 32; d > 0; d >>= 1) local += __shfl_down(local, d, 64);
    if (lane == 0) s_red[wid] = local;
    __syncthreads();
    if (tid == 0)
        partial[blockIdx.x] = s_red[0] + s_red[1] + s_red[2] + s_red[3];
}

// ---------------------------------------------------------------------------
// Final reduction of per-block partials (single block, no atomics).
// ---------------------------------------------------------------------------
__global__ __launch_bounds__(256) void reduce_kernel(
    const float* __restrict__ partial, float* __restrict__ out)
{
    float s = 0.f;
    for (int t = threadIdx.x; t < GRID; t += 256) s += partial[t];
    const int lane = threadIdx.x & 63;
#pragma unroll
    for (int d = 32; d > 0; d >>= 1) s += __shfl_down(s, d, 64);
    __shared__ float sred[4];
    if (lane == 0) sred[threadIdx.x >> 6] = s;
    __syncthreads();
    if (threadIdx.x == 0)
        out[0] = sred[0] + sred[1] + sred[2] + sred[3];
}

extern "C" void kernel_launch(void* const* d_in, const int* in_sizes, int n_in,
                              void* d_out, int out_size, void* d_ws, size_t ws_size,
                              hipStream_t stream)
{
    const float* pd  = (const float*)d_in[0];
    const float* gt  = (const float*)d_in[1];
    const float* sd  = (const float*)d_in[2];
    const float* w   = (const float*)d_in[3];
    const float* ps0 = (const float*)d_in[4];
    const float* pw0 = (const float*)d_in[5];
    const float* ps1 = (const float*)d_in[6];
    const float* pw1 = (const float*)d_in[7];
    const float* e0  = (const float*)d_in[8];
    const float* e1  = (const float*)d_in[9];
    const int* i0    = (const int*)d_in[10];
    const int* i1    = (const int*)d_in[11];

    float* partial = (float*)d_ws;  // GRID floats; every slot written each call

    hipLaunchKernelGGL(fused_kernel, dim3(GRID), dim3(256), 0, stream,
                       pd, gt, sd, w, ps0, pw0, ps1, pw1,
                       e0, i0, e1, i1, partial);
    hipLaunchKernelGGL(reduce_kernel, dim3(1), dim3(256), 0, stream,
                       partial, (float*)d_out);
}